// Round 1
// baseline (160837.939 us; speedup 1.0000x reference)
//
#include <hip/hip_runtime.h>
#include <math.h>

#define BB    32
#define TT    100
#define INPUT 132
#define HH    1024
#define GG    4096
#define OUTC  132
#define KC    128

// ---------------------------------------------------------------------------
// Precompute W_comb[j][k] = sum_m W_ih1[j][m] * W_dec[m][k]   (4096 x 1024)
// grid 1024 = 64 j-tiles x 16 k-tiles, tile 64x64, block 256
// ---------------------------------------------------------------------------
__global__ __launch_bounds__(256)
void comb_kernel(const float* __restrict__ Wih1, const float* __restrict__ Wdec,
                 float* __restrict__ Wcomb)
{
    __shared__ float wiT[INPUT][64];   // Wih1 tile transposed [m][j]
    __shared__ float wd[INPUT][64];    // Wdec tile [m][k]
    const int tid = threadIdx.x;
    const int jt = (blockIdx.x >> 4) << 6;
    const int kt = (blockIdx.x & 15) << 6;

    for (int i = tid; i < 64 * INPUT; i += 256) {
        const int j = i / INPUT, m = i % INPUT;
        wiT[m][j] = Wih1[(size_t)(jt + j) * INPUT + m];
    }
    for (int i = tid; i < INPUT * 64; i += 256) {
        const int m = i >> 6, k = i & 63;
        wd[m][k] = Wdec[(size_t)m * HH + kt + k];
    }
    __syncthreads();

    const int jl = (tid >> 4) << 2;
    const int kl = (tid & 15) << 2;
    float a[4][4];
#pragma unroll
    for (int x = 0; x < 4; ++x)
#pragma unroll
        for (int y = 0; y < 4; ++y) a[x][y] = 0.f;

    for (int m = 0; m < INPUT; ++m) {
        const float4 wj = *(const float4*)&wiT[m][jl];
        const float4 wk = *(const float4*)&wd[m][kl];
        a[0][0] += wj.x * wk.x; a[0][1] += wj.x * wk.y; a[0][2] += wj.x * wk.z; a[0][3] += wj.x * wk.w;
        a[1][0] += wj.y * wk.x; a[1][1] += wj.y * wk.y; a[1][2] += wj.y * wk.z; a[1][3] += wj.y * wk.w;
        a[2][0] += wj.z * wk.x; a[2][1] += wj.z * wk.y; a[2][2] += wj.z * wk.z; a[2][3] += wj.z * wk.w;
        a[3][0] += wj.w * wk.x; a[3][1] += wj.w * wk.y; a[3][2] += wj.w * wk.z; a[3][3] += wj.w * wk.w;
    }
#pragma unroll
    for (int jj = 0; jj < 4; ++jj) {
        float4 v; v.x = a[jj][0]; v.y = a[jj][1]; v.z = a[jj][2]; v.w = a[jj][3];
        *(float4*)&Wcomb[(size_t)(jt + jl + jj) * HH + kt + kl] = v;
    }
}

// ---------------------------------------------------------------------------
// Bias precompute: bc_gt = b_ih1+b_hh1 ; bc_ng = bc_gt + W_ih1 @ b_dec ;
// bc2, bc3 similarly summed.
// ---------------------------------------------------------------------------
__global__ __launch_bounds__(256)
void bias_kernel(const float* __restrict__ Wih1, const float* __restrict__ bdec,
                 const float* __restrict__ bih1, const float* __restrict__ bhh1,
                 const float* __restrict__ bih2, const float* __restrict__ bhh2,
                 const float* __restrict__ bih3, const float* __restrict__ bhh3,
                 float* __restrict__ bc_gt, float* __restrict__ bc_ng,
                 float* __restrict__ bc2, float* __restrict__ bc3)
{
    const int j = blockIdx.x * 256 + threadIdx.x;
    if (j >= GG) return;
    const float s1 = bih1[j] + bhh1[j];
    float cb = 0.f;
    for (int m = 0; m < INPUT; ++m) cb += Wih1[(size_t)j * INPUT + m] * bdec[m];
    bc_gt[j] = s1;
    bc_ng[j] = s1 + cb;
    bc2[j] = bih2[j] + bhh2[j];
    bc3[j] = bih3[j] + bhh3[j];
}

// ---------------------------------------------------------------------------
// One timestep. grid 256 (WG owns 4 hidden units u = 4*wg..+3, all 4 gates,
// all 3 cells = 48 columns), block 512 = 32 batch x 16 k-slices.
// t in [0,100]; t==100 is decode-only (writes out[99]).
// ---------------------------------------------------------------------------
template <bool USE_GT>
__global__ __launch_bounds__(512)
void phase_kernel(const float* __restrict__ seq,
                  const float* __restrict__ Wih1, const float* __restrict__ Whh1,
                  const float* __restrict__ Wih2, const float* __restrict__ Whh2,
                  const float* __restrict__ Wih3, const float* __restrict__ Whh3,
                  const float* __restrict__ Wdec, const float* __restrict__ bdec,
                  const float* __restrict__ Wcomb,
                  const float* __restrict__ bc_gt, const float* __restrict__ bc_ng,
                  const float* __restrict__ bc2, const float* __restrict__ bc3,
                  const float* __restrict__ hr, float* __restrict__ hw,
                  float* __restrict__ cst, float* __restrict__ outp, int t)
{
    __shared__ float hc[3][BB][132];      // h chunk stage, +4 pad (16B align, 4-way banks)
    __shared__ float red[16][48][BB];     // partials [slice][col][b], conflict-free
    __shared__ float dpart[BB][16];

    const int tid = threadIdx.x;
    const int wg  = blockIdx.x;
    const int ubase = wg << 2;
    const int b  = tid & 31;
    const int cg = tid >> 5;              // k-slice 0..15

    const bool do_gates = (t < TT);
    const bool do_dec = (t >= 1) && (wg < OUTC);

    float acc[3][4][4];
#pragma unroll
    for (int c = 0; c < 3; ++c)
#pragma unroll
        for (int g = 0; g < 4; ++g)
#pragma unroll
            for (int d = 0; d < 4; ++d) acc[c][g][d] = 0.f;
    float dec = 0.f;

    float* xs = &red[0][0][0];            // alias: [BB][136], used before red

    if (USE_GT && do_gates) {
        // stage ground-truth frame x = real_seq[:, t, :]
        for (int i = tid; i < BB * 33; i += 512) {
            const int bb = i / 33, q = i % 33;
            *(float4*)&xs[bb * 136 + q * 4] =
                *(const float4*)&seq[(size_t)bb * (TT * INPUT) + (size_t)t * INPUT + q * 4];
        }
        __syncthreads();
        for (int kq = cg; kq < 33; kq += 16) {
            const float4 xq = *(const float4*)&xs[b * 136 + kq * 4];
#pragma unroll
            for (int g = 0; g < 4; ++g)
#pragma unroll
                for (int du = 0; du < 4; ++du) {
                    const float4 wq = *(const float4*)&Wih1[(size_t)((g << 10) + ubase + du) * INPUT + kq * 4];
                    acc[0][g][du] += wq.x * xq.x + wq.y * xq.y + wq.z * xq.z + wq.w * xq.w;
                }
        }
    }

    for (int k0 = 0; k0 < HH; k0 += KC) {
        __syncthreads();
        for (int i = tid; i < 3 * BB * (KC / 4); i += 512) {
            const int cell = i >> 10;
            const int rem  = i & 1023;
            const int row  = rem >> 5;
            const int c4   = rem & 31;
            *(float4*)&hc[cell][row][c4 * 4] =
                *(const float4*)&hr[(size_t)(cell * BB + row) * HH + k0 + c4 * 4];
        }
        __syncthreads();
        if (do_gates) {
#pragma unroll
            for (int q = 0; q < 2; ++q) {
                const int kk = (cg * 2 + q) * 4;
                const int kglob = k0 + kk;
                const float4 h0q = *(const float4*)&hc[0][b][kk];
                const float4 h1q = *(const float4*)&hc[1][b][kk];
                const float4 h2q = *(const float4*)&hc[2][b][kk];
#pragma unroll
                for (int g = 0; g < 4; ++g)
#pragma unroll
                    for (int du = 0; du < 4; ++du) {
                        const size_t off = (size_t)((g << 10) + ubase + du) * HH + kglob;
                        float4 w;
                        w = *(const float4*)&Whh1[off];
                        acc[0][g][du] += w.x * h0q.x + w.y * h0q.y + w.z * h0q.z + w.w * h0q.w;
                        if (!USE_GT) {
                            w = *(const float4*)&Wcomb[off];
                            acc[0][g][du] += w.x * h2q.x + w.y * h2q.y + w.z * h2q.z + w.w * h2q.w;
                        }
                        w = *(const float4*)&Wih2[off];
                        acc[1][g][du] += w.x * h0q.x + w.y * h0q.y + w.z * h0q.z + w.w * h0q.w;
                        w = *(const float4*)&Whh2[off];
                        acc[1][g][du] += w.x * h1q.x + w.y * h1q.y + w.z * h1q.z + w.w * h1q.w;
                        w = *(const float4*)&Wih3[off];
                        acc[2][g][du] += w.x * h1q.x + w.y * h1q.y + w.z * h1q.z + w.w * h1q.w;
                        w = *(const float4*)&Whh3[off];
                        acc[2][g][du] += w.x * h2q.x + w.y * h2q.y + w.z * h2q.z + w.w * h2q.w;
                    }
                if (do_dec) {
                    const float4 wq = *(const float4*)&Wdec[(size_t)wg * HH + kglob];
                    dec += wq.x * h2q.x + wq.y * h2q.y + wq.z * h2q.z + wq.w * h2q.w;
                }
            }
        } else if (do_dec) {
#pragma unroll
            for (int q = 0; q < 2; ++q) {
                const int kk = (cg * 2 + q) * 4;
                const float4 h2q = *(const float4*)&hc[2][b][kk];
                const float4 wq = *(const float4*)&Wdec[(size_t)wg * HH + k0 + kk];
                dec += wq.x * h2q.x + wq.y * h2q.y + wq.z * h2q.z + wq.w * h2q.w;
            }
        }
    }

    if (do_gates) {
#pragma unroll
        for (int c = 0; c < 3; ++c)
#pragma unroll
            for (int g = 0; g < 4; ++g)
#pragma unroll
                for (int du = 0; du < 4; ++du)
                    red[cg][c * 16 + g * 4 + du][b] = acc[c][g][du];
    }
    if (do_dec) dpart[b][cg] = dec;
    __syncthreads();

    if (do_gates && tid < 384) {
        const int cell = tid >> 7;
        const int r  = tid & 127;
        const int du = r >> 5;
        const int bb = r & 31;
        const int u  = ubase + du;
        float gate[4];
#pragma unroll
        for (int g = 0; g < 4; ++g) {
            float s = 0.f;
#pragma unroll
            for (int c = 0; c < 16; ++c) s += red[c][cell * 16 + g * 4 + du][bb];
            gate[g] = s;
        }
        const float* bias = (cell == 0) ? (USE_GT ? bc_gt : bc_ng) : ((cell == 1) ? bc2 : bc3);
        const float gi = gate[0] + bias[u];
        const float gf = gate[1] + bias[HH + u];
        const float gg = gate[2] + bias[2 * HH + u];
        const float go = gate[3] + bias[3 * HH + u];
        const size_t si = (size_t)(cell * BB + bb) * HH + u;
        const float cold = cst[si];
        const float is = 1.f / (1.f + expf(-gi));
        const float fs = 1.f / (1.f + expf(-gf));
        const float os = 1.f / (1.f + expf(-go));
        const float cn = fs * cold + is * tanhf(gg);
        const float hn = os * tanhf(cn);
        cst[si] = cn;
        hw[si]  = hn;
    }
    if (do_dec && tid < BB) {
        float s = 0.f;
#pragma unroll
        for (int c = 0; c < 16; ++c) s += dpart[tid][c];
        outp[(size_t)tid * (TT * OUTC) + (size_t)(t - 1) * OUTC + wg] = s + bdec[wg];
    }
}

// ---------------------------------------------------------------------------
extern "C" void kernel_launch(void* const* d_in, const int* in_sizes, int n_in,
                              void* d_out, int out_size, void* d_ws, size_t ws_size,
                              hipStream_t stream)
{
    const float* seq  = (const float*)d_in[0];
    const float* Wih1 = (const float*)d_in[1];
    const float* Whh1 = (const float*)d_in[2];
    const float* bih1 = (const float*)d_in[3];
    const float* bhh1 = (const float*)d_in[4];
    const float* Wih2 = (const float*)d_in[5];
    const float* Whh2 = (const float*)d_in[6];
    const float* bih2 = (const float*)d_in[7];
    const float* bhh2 = (const float*)d_in[8];
    const float* Wih3 = (const float*)d_in[9];
    const float* Whh3 = (const float*)d_in[10];
    const float* bih3 = (const float*)d_in[11];
    const float* bhh3 = (const float*)d_in[12];
    const float* Wdec = (const float*)d_in[13];
    const float* bdec = (const float*)d_in[14];
    float* outp = (float*)d_out;
    float* ws   = (float*)d_ws;

    float* Wcomb = ws;                       // 4096*1024
    float* bc_gt = ws + 4194304;             // 4096
    float* bc_ng = bc_gt + 4096;
    float* bc2   = bc_ng + 4096;
    float* bc3   = bc2 + 4096;
    float* hbuf  = bc3 + 4096;               // 2 * 3*32*1024
    float* cst   = hbuf + 2 * 98304;         // 3*32*1024

    // zero h (read buffer at t=0) and c state (ws is poisoned each call)
    hipMemsetAsync(hbuf, 0, (size_t)(2 * 98304 + 98304) * sizeof(float), stream);

    comb_kernel<<<dim3(1024), dim3(256), 0, stream>>>(Wih1, Wdec, Wcomb);
    bias_kernel<<<dim3(16), dim3(256), 0, stream>>>(Wih1, bdec, bih1, bhh1, bih2, bhh2,
                                                    bih3, bhh3, bc_gt, bc_ng, bc2, bc3);

    for (int t = 0; t <= TT; ++t) {
        const float* hr = hbuf + (t & 1) * 98304;
        float* hw = hbuf + ((t + 1) & 1) * 98304;
        const bool gt = (t % 10) < 5;
        if (gt)
            phase_kernel<true><<<dim3(256), dim3(512), 0, stream>>>(
                seq, Wih1, Whh1, Wih2, Whh2, Wih3, Whh3, Wdec, bdec, Wcomb,
                bc_gt, bc_ng, bc2, bc3, hr, hw, cst, outp, t);
        else
            phase_kernel<false><<<dim3(256), dim3(512), 0, stream>>>(
                seq, Wih1, Whh1, Wih2, Whh2, Wih3, Whh3, Wdec, bdec, Wcomb,
                bc_gt, bc_ng, bc2, bc3, hr, hw, cst, outp, t);
    }
}

// Round 2
// 89553.436 us; speedup vs baseline: 1.7960x; 1.7960x over previous
//
#include <hip/hip_runtime.h>
#include <math.h>

#define BB    32
#define TT    100
#define INPUT 132
#define HH    1024
#define GG    4096
#define OUTC  132
#define SW    96      // transposed state row width: 3 cells * 32 batch

// ---------------------------------------------------------------------------
// Precompute W_comb[j][k] = sum_m W_ih1[j][m] * W_dec[m][k]   (4096 x 1024)
// ---------------------------------------------------------------------------
__global__ __launch_bounds__(256)
void comb_kernel(const float* __restrict__ Wih1, const float* __restrict__ Wdec,
                 float* __restrict__ Wcomb)
{
    __shared__ float wiT[INPUT][64];   // Wih1 tile transposed [m][j]
    __shared__ float wd[INPUT][64];    // Wdec tile [m][k]
    const int tid = threadIdx.x;
    const int jt = (blockIdx.x >> 4) << 6;
    const int kt = (blockIdx.x & 15) << 6;

    for (int i = tid; i < 64 * INPUT; i += 256) {
        const int j = i / INPUT, m = i % INPUT;
        wiT[m][j] = Wih1[(size_t)(jt + j) * INPUT + m];
    }
    for (int i = tid; i < INPUT * 64; i += 256) {
        const int m = i >> 6, k = i & 63;
        wd[m][k] = Wdec[(size_t)m * HH + kt + k];
    }
    __syncthreads();

    const int jl = (tid >> 4) << 2;
    const int kl = (tid & 15) << 2;
    float a[4][4];
#pragma unroll
    for (int x = 0; x < 4; ++x)
#pragma unroll
        for (int y = 0; y < 4; ++y) a[x][y] = 0.f;

    for (int m = 0; m < INPUT; ++m) {
        const float4 wj = *(const float4*)&wiT[m][jl];
        const float4 wk = *(const float4*)&wd[m][kl];
        a[0][0] += wj.x * wk.x; a[0][1] += wj.x * wk.y; a[0][2] += wj.x * wk.z; a[0][3] += wj.x * wk.w;
        a[1][0] += wj.y * wk.x; a[1][1] += wj.y * wk.y; a[1][2] += wj.y * wk.z; a[1][3] += wj.y * wk.w;
        a[2][0] += wj.z * wk.x; a[2][1] += wj.z * wk.y; a[2][2] += wj.z * wk.z; a[2][3] += wj.z * wk.w;
        a[3][0] += wj.w * wk.x; a[3][1] += wj.w * wk.y; a[3][2] += wj.w * wk.z; a[3][3] += wj.w * wk.w;
    }
#pragma unroll
    for (int jj = 0; jj < 4; ++jj) {
        float4 v; v.x = a[jj][0]; v.y = a[jj][1]; v.z = a[jj][2]; v.w = a[jj][3];
        *(float4*)&Wcomb[(size_t)(jt + jl + jj) * HH + kt + kl] = v;
    }
}

// ---------------------------------------------------------------------------
// Bias precompute
// ---------------------------------------------------------------------------
__global__ __launch_bounds__(256)
void bias_kernel(const float* __restrict__ Wih1, const float* __restrict__ bdec,
                 const float* __restrict__ bih1, const float* __restrict__ bhh1,
                 const float* __restrict__ bih2, const float* __restrict__ bhh2,
                 const float* __restrict__ bih3, const float* __restrict__ bhh3,
                 float* __restrict__ bc_gt, float* __restrict__ bc_ng,
                 float* __restrict__ bc2, float* __restrict__ bc3)
{
    const int j = blockIdx.x * 256 + threadIdx.x;
    if (j >= GG) return;
    const float s1 = bih1[j] + bhh1[j];
    float cb = 0.f;
    for (int m = 0; m < INPUT; ++m) cb += Wih1[(size_t)j * INPUT + m] * bdec[m];
    bc_gt[j] = s1;
    bc_ng[j] = s1 + cb;
    bc2[j] = bih2[j] + bhh2[j];
    bc3[j] = bih3[j] + bhh3[j];
}

__device__ __forceinline__ float4 ldw(const float* __restrict__ p, int byteoff) {
    return *(const float4*)((const char*)p + byteoff);
}

// ---------------------------------------------------------------------------
// One timestep. grid 256 (WG owns 4 hidden units, all 4 gates, 3 cells = 48
// cols), block 512 = 32 batch x 16 contiguous k-slices of 64.
// States stored TRANSPOSED: hT/cstT[k or u][cell*32 + b] (coalesced across b).
// __launch_bounds__(512,2): 2 waves/SIMD -> 256 VGPR cap (spill fix; r0 had
// 128-cap spill = 3.1 GB scratch writes/dispatch).
// ---------------------------------------------------------------------------
template <bool USE_GT>
__global__ __launch_bounds__(512, 2)
void phase_kernel(const float* __restrict__ seq,
                  const float* __restrict__ Wih1, const float* __restrict__ Whh1,
                  const float* __restrict__ Wih2, const float* __restrict__ Whh2,
                  const float* __restrict__ Wih3, const float* __restrict__ Whh3,
                  const float* __restrict__ Wdec, const float* __restrict__ bdec,
                  const float* __restrict__ Wcomb,
                  const float* __restrict__ bc_gt, const float* __restrict__ bc_ng,
                  const float* __restrict__ bc2, const float* __restrict__ bc3,
                  const float* __restrict__ hT_r, float* __restrict__ hT_w,
                  float* __restrict__ cstT, float* __restrict__ outp, int t)
{
    __shared__ float red[8][48][BB];   // [slice-pair][col][b], conflict-free
    __shared__ float dpart[8][BB];

    const int tid = threadIdx.x;
    const int wg  = blockIdx.x;
    const int ubase = wg << 2;
    const int b  = tid & 31;
    const int cg = tid >> 5;           // k-slice 0..15
    const int k0 = cg << 6;            // this thread's k range [k0, k0+64)

    const bool do_gates = (t < TT);
    const bool do_dec = (t >= 1) && (wg < OUTC);

    float acc[48];
#pragma unroll
    for (int i = 0; i < 48; ++i) acc[i] = 0.f;
    float dec = 0.f;

    if (do_gates) {
        if (USE_GT) {
            // x-part: x = real_seq[:, t, :], split 33 float4 chunks across cg
            for (int kq = cg; kq < 33; kq += 16) {
                const float4 xq = *(const float4*)&seq[(size_t)b * (TT * INPUT) +
                                                       (size_t)t * INPUT + (kq << 2)];
#pragma unroll
                for (int j = 0; j < 16; ++j) {
                    const int row = ((j >> 2) << 10) + ubase + (j & 3);
                    const float4 w = ldw(Wih1, (row * INPUT + (kq << 2)) * 4);
                    acc[j] += w.x * xq.x + w.y * xq.y + w.z * xq.z + w.w * xq.w;
                }
            }
        }

        // 16 row byte-offsets shared by all HH-stride matrices
        int off[16];
#pragma unroll
        for (int j = 0; j < 16; ++j)
            off[j] = (((((j >> 2) << 10) + ubase + (j & 3)) * HH) + k0) * 4;
        const int doff = (wg * HH + k0) * 4;

#pragma unroll 1
        for (int kv = 0; kv < 16; ++kv) {
            float h0[4], h1[4], h2[4];
            const float* hp = hT_r + (size_t)(k0 + (kv << 2)) * SW + b;
#pragma unroll
            for (int j = 0; j < 4; ++j) {
                h0[j] = hp[j * SW];
                h1[j] = hp[j * SW + 32];
                h2[j] = hp[j * SW + 64];
            }
            const int kb = kv << 4;
#pragma unroll
            for (int j = 0; j < 16; ++j) {
                float4 w;
                w = ldw(Whh1, off[j] + kb);
                acc[j]      += w.x * h0[0] + w.y * h0[1] + w.z * h0[2] + w.w * h0[3];
                if (!USE_GT) {
                    w = ldw(Wcomb, off[j] + kb);
                    acc[j]  += w.x * h2[0] + w.y * h2[1] + w.z * h2[2] + w.w * h2[3];
                }
                w = ldw(Wih2, off[j] + kb);
                acc[16 + j] += w.x * h0[0] + w.y * h0[1] + w.z * h0[2] + w.w * h0[3];
                w = ldw(Whh2, off[j] + kb);
                acc[16 + j] += w.x * h1[0] + w.y * h1[1] + w.z * h1[2] + w.w * h1[3];
                w = ldw(Wih3, off[j] + kb);
                acc[32 + j] += w.x * h1[0] + w.y * h1[1] + w.z * h1[2] + w.w * h1[3];
                w = ldw(Whh3, off[j] + kb);
                acc[32 + j] += w.x * h2[0] + w.y * h2[1] + w.z * h2[2] + w.w * h2[3];
            }
            if (do_dec) {
                const float4 w = ldw(Wdec, doff + kb);
                dec += w.x * h2[0] + w.y * h2[1] + w.z * h2[2] + w.w * h2[3];
            }
        }
    } else if (do_dec) {
        const int doff = (wg * HH + k0) * 4;
#pragma unroll 1
        for (int kv = 0; kv < 16; ++kv) {
            const float* hp = hT_r + (size_t)(k0 + (kv << 2)) * SW + b;
            float h2[4];
#pragma unroll
            for (int j = 0; j < 4; ++j) h2[j] = hp[j * SW + 64];
            const float4 w = ldw(Wdec, doff + (kv << 4));
            dec += w.x * h2[0] + w.y * h2[1] + w.z * h2[2] + w.w * h2[3];
        }
    }

    // pre-reduce slice pairs within the wave (lanes l and l^32 share b)
    if (do_gates) {
#pragma unroll
        for (int i = 0; i < 48; ++i) acc[i] += __shfl_xor(acc[i], 32);
        if (!(cg & 1)) {
            const int s = cg >> 1;
#pragma unroll
            for (int i = 0; i < 48; ++i) red[s][i][b] = acc[i];
        }
    }
    if (do_dec) {
        dec += __shfl_xor(dec, 32);
        if (!(cg & 1)) dpart[cg >> 1][b] = dec;
    }
    __syncthreads();

    if (do_gates && tid < 384) {
        const int cell = tid >> 7;
        const int r  = tid & 127;
        const int du = r >> 5;
        const int bb = r & 31;
        const int u  = ubase + du;
        float gate[4];
#pragma unroll
        for (int g = 0; g < 4; ++g) {
            float s = 0.f;
#pragma unroll
            for (int sl = 0; sl < 8; ++sl) s += red[sl][cell * 16 + g * 4 + du][bb];
            gate[g] = s;
        }
        const float* bias = (cell == 0) ? (USE_GT ? bc_gt : bc_ng)
                                        : ((cell == 1) ? bc2 : bc3);
        const float gi = gate[0] + bias[u];
        const float gf = gate[1] + bias[HH + u];
        const float gg = gate[2] + bias[2 * HH + u];
        const float go = gate[3] + bias[3 * HH + u];
        const int si = u * SW + cell * 32 + bb;      // transposed state index
        const float cold = cstT[si];
        const float is = 1.f / (1.f + expf(-gi));
        const float fs = 1.f / (1.f + expf(-gf));
        const float os = 1.f / (1.f + expf(-go));
        const float cn = fs * cold + is * tanhf(gg);
        const float hn = os * tanhf(cn);
        cstT[si] = cn;
        hT_w[si] = hn;
    }
    if (do_dec && tid < BB) {
        float s = 0.f;
#pragma unroll
        for (int sl = 0; sl < 8; ++sl) s += dpart[sl][tid];
        outp[(size_t)tid * (TT * OUTC) + (size_t)(t - 1) * OUTC + wg] = s + bdec[wg];
    }
}

// ---------------------------------------------------------------------------
extern "C" void kernel_launch(void* const* d_in, const int* in_sizes, int n_in,
                              void* d_out, int out_size, void* d_ws, size_t ws_size,
                              hipStream_t stream)
{
    const float* seq  = (const float*)d_in[0];
    const float* Wih1 = (const float*)d_in[1];
    const float* Whh1 = (const float*)d_in[2];
    const float* bih1 = (const float*)d_in[3];
    const float* bhh1 = (const float*)d_in[4];
    const float* Wih2 = (const float*)d_in[5];
    const float* Whh2 = (const float*)d_in[6];
    const float* bih2 = (const float*)d_in[7];
    const float* bhh2 = (const float*)d_in[8];
    const float* Wih3 = (const float*)d_in[9];
    const float* Whh3 = (const float*)d_in[10];
    const float* bih3 = (const float*)d_in[11];
    const float* bhh3 = (const float*)d_in[12];
    const float* Wdec = (const float*)d_in[13];
    const float* bdec = (const float*)d_in[14];
    float* outp = (float*)d_out;
    float* ws   = (float*)d_ws;

    float* Wcomb = ws;                       // 4096*1024
    float* bc_gt = ws + 4194304;             // 4096 each
    float* bc_ng = bc_gt + 4096;
    float* bc2   = bc_ng + 4096;
    float* bc3   = bc2 + 4096;
    float* hbuf  = bc3 + 4096;               // 2 x 1024*96 (transposed h)
    float* cstT  = hbuf + 2 * (HH * SW);     // 1024*96 (transposed c)

    // zero h ping-pong + c state (ws is poisoned 0xAA each call)
    hipMemsetAsync(hbuf, 0, (size_t)(3 * HH * SW) * sizeof(float), stream);

    comb_kernel<<<dim3(1024), dim3(256), 0, stream>>>(Wih1, Wdec, Wcomb);
    bias_kernel<<<dim3(16), dim3(256), 0, stream>>>(Wih1, bdec, bih1, bhh1, bih2, bhh2,
                                                    bih3, bhh3, bc_gt, bc_ng, bc2, bc3);

    for (int t = 0; t <= TT; ++t) {
        const float* hr = hbuf + (t & 1) * (HH * SW);
        float* hw = hbuf + ((t + 1) & 1) * (HH * SW);
        const bool gt = (t % 10) < 5;
        if (gt)
            phase_kernel<true><<<dim3(256), dim3(512), 0, stream>>>(
                seq, Wih1, Whh1, Wih2, Whh2, Wih3, Whh3, Wdec, bdec, Wcomb,
                bc_gt, bc_ng, bc2, bc3, hr, hw, cstT, outp, t);
        else
            phase_kernel<false><<<dim3(256), dim3(512), 0, stream>>>(
                seq, Wih1, Whh1, Wih2, Whh2, Wih3, Whh3, Wdec, bdec, Wcomb,
                bc_gt, bc_ng, bc2, bc3, hr, hw, cstT, outp, t);
    }
}

// Round 4
// 10603.086 us; speedup vs baseline: 15.1690x; 8.4460x over previous
//
#include <hip/hip_runtime.h>
#include <math.h>

#define BB    32
#define TT    100
#define INPUT 132
#define HH    1024
#define GG    4096
#define OUTC  132
#define SW    96      // transposed state row width: 3 cells * 32 batch

// ---------------------------------------------------------------------------
// Precompute W_comb[j][k] = sum_m W_ih1[j][m] * W_dec[m][k]   (4096 x 1024)
// ---------------------------------------------------------------------------
__global__ __launch_bounds__(256)
void comb_kernel(const float* __restrict__ Wih1, const float* __restrict__ Wdec,
                 float* __restrict__ Wcomb)
{
    __shared__ float wiT[INPUT][64];   // Wih1 tile transposed [m][j]
    __shared__ float wd[INPUT][64];    // Wdec tile [m][k]
    const int tid = threadIdx.x;
    const int jt = (blockIdx.x >> 4) << 6;
    const int kt = (blockIdx.x & 15) << 6;

    for (int i = tid; i < 64 * INPUT; i += 256) {
        const int j = i / INPUT, m = i % INPUT;
        wiT[m][j] = Wih1[(size_t)(jt + j) * INPUT + m];
    }
    for (int i = tid; i < INPUT * 64; i += 256) {
        const int m = i >> 6, k = i & 63;
        wd[m][k] = Wdec[(size_t)m * HH + kt + k];
    }
    __syncthreads();

    const int jl = (tid >> 4) << 2;
    const int kl = (tid & 15) << 2;
    float a[4][4];
#pragma unroll
    for (int x = 0; x < 4; ++x)
#pragma unroll
        for (int y = 0; y < 4; ++y) a[x][y] = 0.f;

    for (int m = 0; m < INPUT; ++m) {
        const float4 wj = *(const float4*)&wiT[m][jl];
        const float4 wk = *(const float4*)&wd[m][kl];
        a[0][0] += wj.x * wk.x; a[0][1] += wj.x * wk.y; a[0][2] += wj.x * wk.z; a[0][3] += wj.x * wk.w;
        a[1][0] += wj.y * wk.x; a[1][1] += wj.y * wk.y; a[1][2] += wj.y * wk.z; a[1][3] += wj.y * wk.w;
        a[2][0] += wj.z * wk.x; a[2][1] += wj.z * wk.y; a[2][2] += wj.z * wk.z; a[2][3] += wj.z * wk.w;
        a[3][0] += wj.w * wk.x; a[3][1] += wj.w * wk.y; a[3][2] += wj.w * wk.z; a[3][3] += wj.w * wk.w;
    }
#pragma unroll
    for (int jj = 0; jj < 4; ++jj) {
        float4 v; v.x = a[jj][0]; v.y = a[jj][1]; v.z = a[jj][2]; v.w = a[jj][3];
        *(float4*)&Wcomb[(size_t)(jt + jl + jj) * HH + kt + kl] = v;
    }
}

// ---------------------------------------------------------------------------
// Bias precompute
// ---------------------------------------------------------------------------
__global__ __launch_bounds__(256)
void bias_kernel(const float* __restrict__ Wih1, const float* __restrict__ bdec,
                 const float* __restrict__ bih1, const float* __restrict__ bhh1,
                 const float* __restrict__ bih2, const float* __restrict__ bhh2,
                 const float* __restrict__ bih3, const float* __restrict__ bhh3,
                 float* __restrict__ bc_gt, float* __restrict__ bc_ng,
                 float* __restrict__ bc2, float* __restrict__ bc3)
{
    const int j = blockIdx.x * 256 + threadIdx.x;
    if (j >= GG) return;
    const float s1 = bih1[j] + bhh1[j];
    float cb = 0.f;
    for (int m = 0; m < INPUT; ++m) cb += Wih1[(size_t)j * INPUT + m] * bdec[m];
    bc_gt[j] = s1;
    bc_ng[j] = s1 + cb;
    bc2[j] = bih2[j] + bhh2[j];
    bc3[j] = bih3[j] + bhh3[j];
}

__device__ __forceinline__ float4 ldw(const float* __restrict__ p, int byteoff) {
    return *(const float4*)((const char*)p + byteoff);
}
__device__ __forceinline__ float dot4(float4 w, const float* h) {
    return w.x * h[0] + w.y * h[1] + w.z * h[2] + w.w * h[3];
}

// ---------------------------------------------------------------------------
// One timestep. grid 1024: WG owns ONE hidden unit u=wg (all 4 gates, 3 cells
// = 12 rows; weight row index g*1024+u identical across all 6 matrices -> 4
// shared offsets). block 512 = 32 batch x 16 k-slices of 64.
// States TRANSPOSED: hT/cstT[u][cell*32+b]. acc[12] -> ~80 VGPR, no spill.
// __launch_bounds__(512,1): 2nd arg is min BLOCKS/CU (r1 evidence: (512,2)
// capped at 128 VGPR = 2 blocks) -> 1 block/CU = 256 VGPR budget.
// ---------------------------------------------------------------------------
template <bool USE_GT>
__global__ __launch_bounds__(512, 1)
void phase_kernel(const float* __restrict__ seq,
                  const float* __restrict__ Wih1, const float* __restrict__ Whh1,
                  const float* __restrict__ Wih2, const float* __restrict__ Whh2,
                  const float* __restrict__ Wih3, const float* __restrict__ Whh3,
                  const float* __restrict__ Wdec, const float* __restrict__ bdec,
                  const float* __restrict__ Wcomb,
                  const float* __restrict__ bc_gt, const float* __restrict__ bc_ng,
                  const float* __restrict__ bc2, const float* __restrict__ bc3,
                  const float* __restrict__ hT_r, float* __restrict__ hT_w,
                  float* __restrict__ cstT, float* __restrict__ outp, int t)
{
    __shared__ float red[8][12][BB];   // [kslice-pair][cell*4+gate][b]
    __shared__ float dpart[8][BB];

    const int tid = threadIdx.x;
    const int wg  = blockIdx.x;        // hidden unit u
    const int b  = tid & 31;
    const int cg = tid >> 5;           // k-slice 0..15
    const int k0 = cg << 6;            // [k0, k0+64)

    const bool do_gates = (t < TT);
    const bool do_dec = (t >= 1) && (wg < OUTC);

    float acc[12];
#pragma unroll
    for (int i = 0; i < 12; ++i) acc[i] = 0.f;
    float dec = 0.f;

    if (do_gates) {
        if (USE_GT) {
            // x-part: rows g*1024+u of Wih1 (132 cols), x = seq[b, t, :]
            for (int kq = cg; kq < 33; kq += 16) {
                const float4 xq = *(const float4*)&seq[(size_t)b * (TT * INPUT) +
                                                       (size_t)t * INPUT + (kq << 2)];
                const float xv[4] = {xq.x, xq.y, xq.z, xq.w};
#pragma unroll
                for (int g = 0; g < 4; ++g) {
                    const float4 w = ldw(Wih1, (((g << 10) + wg) * INPUT + (kq << 2)) * 4);
                    acc[g] += dot4(w, xv);
                }
            }
        }

        int off[4];
#pragma unroll
        for (int g = 0; g < 4; ++g)
            off[g] = ((((g << 10) + wg) << 10) + k0) << 2;   // (g*1024+u)*1024*4 + k0*4
        const int doff = ((wg << 10) + k0) << 2;

#pragma unroll 1
        for (int kv = 0; kv < 16; ++kv) {
            float h0[4], h1[4], h2[4];
            const float* hp = hT_r + (size_t)(k0 + (kv << 2)) * SW + b;
#pragma unroll
            for (int j = 0; j < 4; ++j) {
                h0[j] = hp[j * SW];
                h1[j] = hp[j * SW + 32];
                h2[j] = hp[j * SW + 64];
            }
            const int kb = kv << 4;
#pragma unroll
            for (int g = 0; g < 4; ++g) {
                const int o = off[g] + kb;
                acc[g]     += dot4(ldw(Whh1, o), h0);
                if (!USE_GT)
                    acc[g] += dot4(ldw(Wcomb, o), h2);
                acc[4 + g] += dot4(ldw(Wih2, o), h0);
                acc[4 + g] += dot4(ldw(Whh2, o), h1);
                acc[8 + g] += dot4(ldw(Wih3, o), h1);
                acc[8 + g] += dot4(ldw(Whh3, o), h2);
            }
            if (do_dec) dec += dot4(ldw(Wdec, doff + kb), h2);
        }
    } else if (do_dec) {
        const int doff = ((wg << 10) + k0) << 2;
#pragma unroll 1
        for (int kv = 0; kv < 16; ++kv) {
            const float* hp = hT_r + (size_t)(k0 + (kv << 2)) * SW + b;
            float h2[4];
#pragma unroll
            for (int j = 0; j < 4; ++j) h2[j] = hp[j * SW + 64];
            dec += dot4(ldw(Wdec, doff + (kv << 4)), h2);
        }
    }

    // pre-reduce k-slice pairs within the wave (lanes l, l^32 share b)
    if (do_gates) {
#pragma unroll
        for (int i = 0; i < 12; ++i) acc[i] += __shfl_xor(acc[i], 32);
        if (!(cg & 1)) {
            const int s = cg >> 1;
#pragma unroll
            for (int i = 0; i < 12; ++i) red[s][i][b] = acc[i];
        }
    }
    if (do_dec) {
        dec += __shfl_xor(dec, 32);
        if (!(cg & 1)) dpart[cg >> 1][b] = dec;
    }
    __syncthreads();

    if (do_gates && tid < 96) {
        const int cell = tid >> 5;
        const int bb = tid & 31;
        float gate[4];
#pragma unroll
        for (int g = 0; g < 4; ++g) {
            float s = 0.f;
#pragma unroll
            for (int sl = 0; sl < 8; ++sl) s += red[sl][cell * 4 + g][bb];
            gate[g] = s;
        }
        const float* bias = (cell == 0) ? (USE_GT ? bc_gt : bc_ng)
                                        : ((cell == 1) ? bc2 : bc3);
        const float gi = gate[0] + bias[wg];
        const float gf = gate[1] + bias[HH + wg];
        const float gg = gate[2] + bias[2 * HH + wg];
        const float go = gate[3] + bias[3 * HH + wg];
        const int si = wg * SW + cell * 32 + bb;     // transposed state index
        const float cold = cstT[si];
        const float is = 1.f / (1.f + expf(-gi));
        const float fs = 1.f / (1.f + expf(-gf));
        const float os = 1.f / (1.f + expf(-go));
        const float cn = fs * cold + is * tanhf(gg);
        const float hn = os * tanhf(cn);
        cstT[si] = cn;
        hT_w[si] = hn;
    }
    if (do_dec && tid < BB) {
        float s = 0.f;
#pragma unroll
        for (int sl = 0; sl < 8; ++sl) s += dpart[sl][tid];
        outp[(size_t)tid * (TT * OUTC) + (size_t)(t - 1) * OUTC + wg] = s + bdec[wg];
    }
}

// ---------------------------------------------------------------------------
extern "C" void kernel_launch(void* const* d_in, const int* in_sizes, int n_in,
                              void* d_out, int out_size, void* d_ws, size_t ws_size,
                              hipStream_t stream)
{
    const float* seq  = (const float*)d_in[0];
    const float* Wih1 = (const float*)d_in[1];
    const float* Whh1 = (const float*)d_in[2];
    const float* bih1 = (const float*)d_in[3];
    const float* bhh1 = (const float*)d_in[4];
    const float* Wih2 = (const float*)d_in[5];
    const float* Whh2 = (const float*)d_in[6];
    const float* bih2 = (const float*)d_in[7];
    const float* bhh2 = (const float*)d_in[8];
    const float* Wih3 = (const float*)d_in[9];
    const float* Whh3 = (const float*)d_in[10];
    const float* bih3 = (const float*)d_in[11];
    const float* bhh3 = (const float*)d_in[12];
    const float* Wdec = (const float*)d_in[13];
    const float* bdec = (const float*)d_in[14];
    float* outp = (float*)d_out;
    float* ws   = (float*)d_ws;

    float* Wcomb = ws;                       // 4096*1024
    float* bc_gt = ws + 4194304;             // 4096 each
    float* bc_ng = bc_gt + 4096;
    float* bc2   = bc_ng + 4096;
    float* bc3   = bc2 + 4096;
    float* hbuf  = bc3 + 4096;               // 2 x 1024*96 (transposed h)
    float* cstT  = hbuf + 2 * (HH * SW);     // 1024*96 (transposed c)

    // zero h ping-pong + c state (ws is poisoned 0xAA each call)
    hipMemsetAsync(hbuf, 0, (size_t)(3 * HH * SW) * sizeof(float), stream);

    comb_kernel<<<dim3(1024), dim3(256), 0, stream>>>(Wih1, Wdec, Wcomb);
    bias_kernel<<<dim3(16), dim3(256), 0, stream>>>(Wih1, bdec, bih1, bhh1, bih2, bhh2,
                                                    bih3, bhh3, bc_gt, bc_ng, bc2, bc3);

    for (int t = 0; t <= TT; ++t) {
        const float* hr = hbuf + (t & 1) * (HH * SW);
        float* hw = hbuf + ((t + 1) & 1) * (HH * SW);
        const bool gt = (t % 10) < 5;
        if (gt)
            phase_kernel<true><<<dim3(1024), dim3(512), 0, stream>>>(
                seq, Wih1, Whh1, Wih2, Whh2, Wih3, Whh3, Wdec, bdec, Wcomb,
                bc_gt, bc_ng, bc2, bc3, hr, hw, cstT, outp, t);
        else
            phase_kernel<false><<<dim3(1024), dim3(512), 0, stream>>>(
                seq, Wih1, Whh1, Wih2, Whh2, Wih3, Whh3, Wdec, bdec, Wcomb,
                bc_gt, bc_ng, bc2, bc3, hr, hw, cstT, outp, t);
    }
}